// Round 12
// baseline (365.430 us; speedup 1.0000x reference)
//
#include <hip/hip_runtime.h>
#include <math.h>

#define EPSV 1e-5f
#define EPB2 1024  // edges per bucket-pass block (782 blocks -> full occupancy)
#define NBP 256    // buckets of 256 nodes (N <= 65536; src packed in 16 bits)
#define CAP 6144   // per-bucket edgeTmp slab capacity (mean 4096, +32 sigma)

typedef short s16x8 __attribute__((ext_vector_type(8)));
typedef float f32x4 __attribute__((ext_vector_type(4)));
typedef unsigned short u16;

#define MFMA(a, b, c) __builtin_amdgcn_mfma_f32_16x16x32_bf16(a, b, c, 0, 0, 0)

__device__ inline u16 f2bf(float f) {
    unsigned u = __float_as_uint(f);
    return (u16)((u + 0x7FFF + ((u >> 16) & 1)) >> 16);
}
__device__ inline float bf2f(u16 h) { return __uint_as_float(((unsigned)h) << 16); }

__device__ inline void split8(const float4& a, const float4& b, s16x8& hv, s16x8& lv) {
    float f[8] = {a.x, a.y, a.z, a.w, b.x, b.y, b.z, b.w};
#pragma unroll
    for (int i = 0; i < 8; ++i) {
        u16 h = f2bf(f[i]);
        hv[i] = (short)h;
        lv[i] = (short)f2bf(f[i] - bf2f(h));
    }
}

// ---------------- setup kernels ----------------

// merged init + weight prep:
//   bx < 320          : fold WT (post_w @ lin_w, transposed, hi/lo)
//   bx < 448          : pre_w transpose/split
//   bx == 448         : folded bias
//   bx >= 449 (y==0)  : zero deg / bucketCur / lsum
__global__ void k_wprep(const float* __restrict__ pre_w, const float* __restrict__ post_w,
                        const float* __restrict__ post_b, const float* __restrict__ lin_w,
                        const float* __restrict__ lin_b, u16* __restrict__ WpT_hi,
                        u16* __restrict__ WpT_lo, u16* __restrict__ WT_hi,
                        u16* __restrict__ WT_lo, float* __restrict__ bpp,
                        int* __restrict__ deg, int* __restrict__ bucketCur,
                        float* __restrict__ lsum, int N) {
    int l = blockIdx.y, bx = blockIdx.x, t = threadIdx.x;
    if (bx < 320) {
        int k = bx, j = t;  // j<192
        int third = j >> 6, c = j & 63;
        float out = 0.f;
        int r = -1;
        if (k < 64) r = (third == 0) ? k : -1;
        else        r = 64 + third * 256 + (k - 64);
        if (r >= 0) {
            const float* pw = post_w + (size_t)(l * 832 + r) * 64;
            const float* lw = lin_w + (size_t)l * 64 * 64;
            float s = 0.f;
            for (int kk = 0; kk < 64; ++kk) s += pw[kk] * lw[kk * 64 + c];
            out = s;
        }
        u16 h = f2bf(out);
        size_t o = ((size_t)l * 192 + j) * 320 + k;
        WT_hi[o] = h;
        WT_lo[o] = f2bf(out - bf2f(h));
    } else if (bx < 448) {
        if (t < 64) {
            int c = bx - 320, k = t;
            float v = pre_w[(size_t)l * 8192 + (size_t)(k + (c >= 64 ? 64 : 0)) * 64 + (c & 63)];
            u16 h = f2bf(v);
            size_t o = ((size_t)l * 128 + c) * 64 + k;
            WpT_hi[o] = h;
            WpT_lo[o] = f2bf(v - bf2f(h));
        }
    } else if (bx == 448) {
        if (t < 64) {
            int c = t;
            const float* pb = post_b + l * 64;
            const float* lw = lin_w + (size_t)l * 64 * 64;
            float s = lin_b[l * 64 + c];
            for (int k = 0; k < 64; ++k) s += pb[k] * lw[k * 64 + c];
            bpp[l * 64 + c] = s;
        }
    } else if (l == 0) {
        int i = (bx - 449) * 192 + t;
        if (i < N) deg[i] = 0;
        if (i < NBP) bucketCur[i] = 0;
        if (i == 0) *lsum = 0.f;
    }
}

// single edge pass: per-node degree histogram + bucket partition into fixed
// per-bucket slabs. 782 blocks of 256 threads (occupancy was the round-11
// bottleneck: 98 blocks = 6% occupancy). Direct scatter, no LDS stage.
// Packed edge word: [bucket:8 | dstLocal:8 | src:16]  (requires N < 65536)
__global__ __launch_bounds__(256) void k_bucket2(const int* __restrict__ src,
                                                 const int* __restrict__ dst, int E,
                                                 int* __restrict__ deg,
                                                 int* __restrict__ bucketCursor,
                                                 unsigned* __restrict__ edgeTmp) {
    __shared__ int cnt[NBP], lpos[NBP];
    int t = threadIdx.x;
    int base = blockIdx.x * EPB2;
    int cntE = min(EPB2, E - base);
    if (t < NBP) cnt[t] = 0;
    __syncthreads();
    unsigned ed[4];
#pragma unroll
    for (int j = 0; j < 4; ++j) {
        int idx = j * 256 + t;
        if (idx < cntE) {
            int e = base + idx;
            unsigned s = (unsigned)src[e];
            unsigned d = (unsigned)dst[e];
            ed[j] = ((d >> 8) << 24) | ((d & 255u) << 16) | s;
            atomicAdd(&cnt[d >> 8], 1);
            atomicAdd(&deg[d], 1);
        }
    }
    __syncthreads();
    if (t < NBP) {
        int c = cnt[t];
        lpos[t] = (c > 0) ? atomicAdd(&bucketCursor[t], c) : 0;
    }
    __syncthreads();
#pragma unroll
    for (int j = 0; j < 4; ++j) {
        int idx = j * 256 + t;
        if (idx < cntE) {
            int b = ed[j] >> 24;
            int p = atomicAdd(&lpos[b], 1);
            if (p < CAP) edgeTmp[(size_t)b * CAP + p] = ed[j];
        }
    }
}

__global__ void k_part(const int* __restrict__ deg, int N, int* __restrict__ part,
                       float* __restrict__ lsum) {
    __shared__ int red[256];
    __shared__ float redf[256];
    int base = blockIdx.x * 1024, t = threadIdx.x;
    int s = 0;
    float ls = 0.f;
#pragma unroll
    for (int j = 0; j < 4; ++j) {
        int i = base + j * 256 + t;
        if (i < N) {
            int d = deg[i];
            s += d;
            ls += logf(fmaxf((float)d, 1.f) + 1.f);
        }
    }
    red[t] = s;
    redf[t] = ls;
    __syncthreads();
    for (int o = 128; o > 0; o >>= 1) {
        if (t < o) { red[t] += red[t + o]; redf[t] += redf[t + o]; }
        __syncthreads();
    }
    if (t == 0) {
        part[blockIdx.x] = red[0];
        atomicAdd(lsum, redf[0]);
    }
}

__global__ void k_scanpart(const int* __restrict__ part, int G, int E,
                           int* __restrict__ partOffs, int* __restrict__ offs, int N) {
    __shared__ int buf[1024];
    int t = threadIdx.x;
    int v = (t < G) ? part[t] : 0;
    buf[t] = v;
    __syncthreads();
    for (int o = 1; o < 1024; o <<= 1) {
        int x = (t >= o) ? buf[t - o] : 0;
        __syncthreads();
        buf[t] += x;
        __syncthreads();
    }
    if (t < G) partOffs[t] = buf[t] - v;
    if (t == 0) offs[N] = E;
}

__global__ void k_offsets(const int* __restrict__ deg, int N,
                          const int* __restrict__ partOffs, const float* __restrict__ lsum,
                          int* __restrict__ offs, float* __restrict__ amp,
                          float* __restrict__ att) {
    __shared__ int buf[1024];
    int base = blockIdx.x * 1024, t = threadIdx.x;
    int v = (base + t < N) ? deg[base + t] : 0;
    buf[t] = v;
    __syncthreads();
    for (int o = 1; o < 1024; o <<= 1) {
        int x = (t >= o) ? buf[t - o] : 0;
        __syncthreads();
        buf[t] += x;
        __syncthreads();
    }
    if (base + t < N) {
        offs[base + t] = partOffs[blockIdx.x] + buf[t] - v;
        float dc = fmaxf((float)v, 1.f);
        float ld = logf(dc + 1.f);
        float avg = *lsum / (float)N;
        amp[base + t] = ld / avg;
        att[base + t] = avg / ld;
    }
}

// counting-sort each 256-node bucket slab in LDS, write u16 srcSorted coalesced
__global__ __launch_bounds__(512) void k_csort(const unsigned* __restrict__ edgeTmp,
                                               const int* __restrict__ bucketCur,
                                               const int* __restrict__ offs,
                                               u16* __restrict__ srcSorted, int N) {
    __shared__ int loffs[257];
    __shared__ int lcur[256];
    __shared__ u16 stageSrc[CAP];
    int b = blockIdx.x, t = threadIdx.x;
    int n0 = b << 8;
    int nodes = min(256, N - n0);
    if (t <= nodes) loffs[t] = offs[n0 + t];
    if (t < 256) lcur[t] = 0;
    __syncthreads();
    int e0 = loffs[0];
    int cnt = min(bucketCur[b], CAP);
    const unsigned* ebase = edgeTmp + (size_t)b * CAP;
    for (int i = t; i < cnt; i += 512) {
        unsigned p = ebase[i];
        int dl = (p >> 16) & 255;
        int r = atomicAdd(&lcur[dl], 1);
        stageSrc[loffs[dl] - e0 + r] = (u16)(p & 0xFFFFu);
    }
    __syncthreads();
    for (int i = t; i < cnt; i += 512) srcSorted[e0 + i] = stageSrc[i];
}

// ---------------- per-layer kernels ----------------

// Ph[M,64] bf16 (+bias), Qh[M,64] bf16 = h[M,64] @ [Wt | Ws] via split-bf16 MFMA
__global__ __launch_bounds__(256) void k_gemm1(const float* __restrict__ h,
                                               const u16* __restrict__ WpT_hi,
                                               const u16* __restrict__ WpT_lo,
                                               const float* __restrict__ pre_b,
                                               u16* __restrict__ Ph, u16* __restrict__ Qh,
                                               int M) {
    __shared__ u16 Ah[64 * 72], Al[64 * 72];
    __shared__ u16 Bh[128 * 72], Bl[128 * 72];
    int t = threadIdx.x, wid = t >> 6, lane = t & 63;
    int rows0 = blockIdx.x * 64;
    int quad = lane >> 4, l16 = lane & 15;
    int wm = wid & 1, wn = wid >> 1;

#pragma unroll
    for (int it = 0; it < 2; ++it) {
        int task = it * 256 + t;
        int r = task >> 3, seg = task & 7;
        int row = rows0 + r;
        float4 v0 = make_float4(0.f, 0.f, 0.f, 0.f), v1 = v0;
        if (row < M) {
            v0 = *(const float4*)&h[(size_t)row * 64 + seg * 8];
            v1 = *(const float4*)&h[(size_t)row * 64 + seg * 8 + 4];
        }
        s16x8 hv, lv;
        split8(v0, v1, hv, lv);
        *(s16x8*)&Ah[r * 72 + seg * 8] = hv;
        *(s16x8*)&Al[r * 72 + seg * 8] = lv;
    }
#pragma unroll
    for (int it = 0; it < 4; ++it) {
        int task = it * 256 + t;
        int c = task >> 3, seg = task & 7;
        *(s16x8*)&Bh[c * 72 + seg * 8] = *(const s16x8*)&WpT_hi[(size_t)c * 64 + seg * 8];
        *(s16x8*)&Bl[c * 72 + seg * 8] = *(const s16x8*)&WpT_lo[(size_t)c * 64 + seg * 8];
    }
    __syncthreads();

    f32x4 acc[2][4];
#pragma unroll
    for (int mt = 0; mt < 2; ++mt)
#pragma unroll
        for (int tt = 0; tt < 4; ++tt) acc[mt][tt] = (f32x4){0.f, 0.f, 0.f, 0.f};

#pragma unroll
    for (int c = 0; c < 2; ++c) {
        s16x8 ah[2], al[2];
#pragma unroll
        for (int mt = 0; mt < 2; ++mt) {
            int r = wm * 32 + mt * 16 + l16;
            ah[mt] = *(s16x8*)&Ah[r * 72 + c * 32 + quad * 8];
            al[mt] = *(s16x8*)&Al[r * 72 + c * 32 + quad * 8];
        }
#pragma unroll
        for (int tt = 0; tt < 4; ++tt) {
            int cc = wn * 64 + tt * 16 + l16;
            s16x8 bh = *(s16x8*)&Bh[cc * 72 + c * 32 + quad * 8];
            s16x8 bl = *(s16x8*)&Bl[cc * 72 + c * 32 + quad * 8];
#pragma unroll
            for (int mt = 0; mt < 2; ++mt) {
                acc[mt][tt] = MFMA(ah[mt], bh, acc[mt][tt]);
                acc[mt][tt] = MFMA(ah[mt], bl, acc[mt][tt]);
                if (wn == 0) acc[mt][tt] = MFMA(al[mt], bh, acc[mt][tt]);
            }
        }
    }

#pragma unroll
    for (int mt = 0; mt < 2; ++mt)
#pragma unroll
        for (int tt = 0; tt < 4; ++tt) {
            int col = wn * 64 + tt * 16 + l16;
#pragma unroll
            for (int r = 0; r < 4; ++r) {
                int row = rows0 + wm * 32 + mt * 16 + quad * 4 + r;
                if (row >= M) continue;
                float v = acc[mt][tt][r];
                if (col < 64) Ph[(size_t)row * 64 + col] = f2bf(v + pre_b[col]);
                else          Qh[(size_t)row * 64 + (col - 64)] = f2bf(v);
            }
        }
}

// aggregation: one wave handles TWO nodes, each 8-deep unrolled
// -> 16 independent gathers in flight; lane = feature.
// Translation-invariant: loop accumulates moments of q only, p added at end.
__global__ __launch_bounds__(256) void k_agg(const u16* __restrict__ Ph,
                                             const u16* __restrict__ Qh,
                                             const int* __restrict__ offs,
                                             const u16* __restrict__ ss,
                                             u16* __restrict__ AGGh, int N) {
    int w = threadIdx.x >> 6, lane = threadIdx.x & 63;
    int i0 = blockIdx.x * 8 + w * 2;
    int i1 = i0 + 1;
    if (i0 >= N) return;
    int beg0 = offs[i0], end0 = offs[i0 + 1];
    int beg1 = 0, end1 = 0;
    if (i1 < N) { beg1 = offs[i1]; end1 = offs[i1 + 1]; }
    float sum0 = 0.f, sqa0 = 0.f, sqb0 = 0.f, mx0 = -3.4e38f, mn0 = 3.4e38f;
    float sum1 = 0.f, sqa1 = 0.f, sqb1 = 0.f, mx1 = -3.4e38f, mn1 = 3.4e38f;
    int e0 = beg0, e1 = beg1;
    while (e0 + 8 <= end0 && e1 + 8 <= end1) {
        float qa[8], qb[8];
#pragma unroll
        for (int j = 0; j < 8; ++j) qa[j] = bf2f(Qh[((int)ss[e0 + j] << 6) + lane]);
#pragma unroll
        for (int j = 0; j < 8; ++j) qb[j] = bf2f(Qh[((int)ss[e1 + j] << 6) + lane]);
        sum0 += ((qa[0] + qa[1]) + (qa[2] + qa[3])) + ((qa[4] + qa[5]) + (qa[6] + qa[7]));
        sqa0 = fmaf(qa[0], qa[0], fmaf(qa[2], qa[2], fmaf(qa[4], qa[4], fmaf(qa[6], qa[6], sqa0))));
        sqb0 = fmaf(qa[1], qa[1], fmaf(qa[3], qa[3], fmaf(qa[5], qa[5], fmaf(qa[7], qa[7], sqb0))));
        mx0 = fmaxf(mx0, fmaxf(fmaxf(fmaxf(qa[0], qa[1]), fmaxf(qa[2], qa[3])),
                               fmaxf(fmaxf(qa[4], qa[5]), fmaxf(qa[6], qa[7]))));
        mn0 = fminf(mn0, fminf(fminf(fminf(qa[0], qa[1]), fminf(qa[2], qa[3])),
                               fminf(fminf(qa[4], qa[5]), fminf(qa[6], qa[7]))));
        sum1 += ((qb[0] + qb[1]) + (qb[2] + qb[3])) + ((qb[4] + qb[5]) + (qb[6] + qb[7]));
        sqa1 = fmaf(qb[0], qb[0], fmaf(qb[2], qb[2], fmaf(qb[4], qb[4], fmaf(qb[6], qb[6], sqa1))));
        sqb1 = fmaf(qb[1], qb[1], fmaf(qb[3], qb[3], fmaf(qb[5], qb[5], fmaf(qb[7], qb[7], sqb1))));
        mx1 = fmaxf(mx1, fmaxf(fmaxf(fmaxf(qb[0], qb[1]), fmaxf(qb[2], qb[3])),
                               fmaxf(fmaxf(qb[4], qb[5]), fmaxf(qb[6], qb[7]))));
        mn1 = fminf(mn1, fminf(fminf(fminf(qb[0], qb[1]), fminf(qb[2], qb[3])),
                               fminf(fminf(qb[4], qb[5]), fminf(qb[6], qb[7]))));
        e0 += 8; e1 += 8;
    }
    for (; e0 + 4 <= end0; e0 += 4) {
        float q0 = bf2f(Qh[((int)ss[e0 + 0] << 6) + lane]);
        float q1 = bf2f(Qh[((int)ss[e0 + 1] << 6) + lane]);
        float q2 = bf2f(Qh[((int)ss[e0 + 2] << 6) + lane]);
        float q3 = bf2f(Qh[((int)ss[e0 + 3] << 6) + lane]);
        sum0 += (q0 + q1) + (q2 + q3);
        sqa0 = fmaf(q0, q0, fmaf(q2, q2, sqa0));
        sqb0 = fmaf(q1, q1, fmaf(q3, q3, sqb0));
        mx0 = fmaxf(mx0, fmaxf(fmaxf(q0, q1), fmaxf(q2, q3)));
        mn0 = fminf(mn0, fminf(fminf(q0, q1), fminf(q2, q3)));
    }
    for (; e1 + 4 <= end1; e1 += 4) {
        float q0 = bf2f(Qh[((int)ss[e1 + 0] << 6) + lane]);
        float q1 = bf2f(Qh[((int)ss[e1 + 1] << 6) + lane]);
        float q2 = bf2f(Qh[((int)ss[e1 + 2] << 6) + lane]);
        float q3 = bf2f(Qh[((int)ss[e1 + 3] << 6) + lane]);
        sum1 += (q0 + q1) + (q2 + q3);
        sqa1 = fmaf(q0, q0, fmaf(q2, q2, sqa1));
        sqb1 = fmaf(q1, q1, fmaf(q3, q3, sqb1));
        mx1 = fmaxf(mx1, fmaxf(fmaxf(q0, q1), fmaxf(q2, q3)));
        mn1 = fminf(mn1, fminf(fminf(q0, q1), fminf(q2, q3)));
    }
    for (; e0 < end0; ++e0) {
        float q = bf2f(Qh[((int)ss[e0] << 6) + lane]);
        sum0 += q; sqa0 = fmaf(q, q, sqa0);
        mx0 = fmaxf(mx0, q); mn0 = fminf(mn0, q);
    }
    for (; e1 < end1; ++e1) {
        float q = bf2f(Qh[((int)ss[e1] << 6) + lane]);
        sum1 += q; sqa1 = fmaf(q, q, sqa1);
        mx1 = fmaxf(mx1, q); mn1 = fminf(mn1, q);
    }
    {
        int deg = end0 - beg0;
        float sq = sqa0 + sqb0;
        float p = bf2f(Ph[(i0 << 6) + lane]);
        float dc = fmaxf((float)deg, 1.f);
        float eq = sum0 / dc;
        float var = fmaxf(sq / dc - eq * eq, 0.f);
        float sd = sqrtf(var + EPSV);
        float mean, vmx, vmn;
        if (deg > 0) { mean = p + eq; vmx = p + mx0; vmn = p + mn0; }
        else         { mean = 0.f; vmx = 0.f; vmn = 0.f; }
        int o = (i0 << 8) + lane;
        AGGh[o] = f2bf(mean);
        AGGh[o + 64] = f2bf(vmx);
        AGGh[o + 128] = f2bf(vmn);
        AGGh[o + 192] = f2bf(sd);
    }
    if (i1 < N) {
        int deg = end1 - beg1;
        float sq = sqa1 + sqb1;
        float p = bf2f(Ph[(i1 << 6) + lane]);
        float dc = fmaxf((float)deg, 1.f);
        float eq = sum1 / dc;
        float var = fmaxf(sq / dc - eq * eq, 0.f);
        float sd = sqrtf(var + EPSV);
        float mean, vmx, vmn;
        if (deg > 0) { mean = p + eq; vmx = p + mx1; vmn = p + mn1; }
        else         { mean = 0.f; vmx = 0.f; vmn = 0.f; }
        int o = (i1 << 8) + lane;
        AGGh[o] = f2bf(mean);
        AGGh[o + 64] = f2bf(vmx);
        AGGh[o + 128] = f2bf(vmn);
        AGGh[o + 192] = f2bf(sd);
    }
}

// gemm2: 128-row blocks, 512 threads (8 waves).
// hOut = hIn + [hIn|AGG] @ WT (192 cols = 3 thirds) combined with amp/att + bpp
__global__ __launch_bounds__(512) void k_gemm2(const float* __restrict__ hIn,
                                               const u16* __restrict__ AGGh,
                                               const u16* __restrict__ WT_hi,
                                               const u16* __restrict__ WT_lo,
                                               const float* __restrict__ bpp,
                                               const float* __restrict__ amp,
                                               const float* __restrict__ att,
                                               float* __restrict__ hOut, int M) {
    __shared__ u16 Ah[128 * 40], Al[128 * 40];  // [row][k-chunk 32], pitch 40
    __shared__ u16 Bh[192 * 40], Bl[192 * 40];  // [col][k-chunk 32], pitch 40
    int t = threadIdx.x, wid = t >> 6, lane = t & 63;
    int rows0 = blockIdx.x * 128;
    int quad = lane >> 4, l16 = lane & 15;
    int wm = wid & 3, wn = wid >> 2;

    f32x4 acc[2][6];  // [mt][cg + third*2]
#pragma unroll
    for (int mt = 0; mt < 2; ++mt)
#pragma unroll
        for (int tt = 0; tt < 6; ++tt) acc[mt][tt] = (f32x4){0.f, 0.f, 0.f, 0.f};

    // ---- Phase 1: k 0..63 over hIn (hi/lo split), cols 0:64 only ----
#pragma unroll
    for (int chunk = 0; chunk < 2; ++chunk) {
        {
            int r = t >> 2, seg = t & 3;  // 128 rows x 4 segs = 512 tasks
            int row = rows0 + r;
            float4 v0 = make_float4(0.f, 0.f, 0.f, 0.f), v1 = v0;
            if (row < M) {
                v0 = *(const float4*)&hIn[(size_t)row * 64 + chunk * 32 + seg * 8];
                v1 = *(const float4*)&hIn[(size_t)row * 64 + chunk * 32 + seg * 8 + 4];
            }
            s16x8 hv, lv;
            split8(v0, v1, hv, lv);
            *(s16x8*)&Ah[r * 40 + seg * 8] = hv;
            *(s16x8*)&Al[r * 40 + seg * 8] = lv;
        }
        if (t < 256) {
            int c = t >> 2, seg = t & 3;  // 64 cols x 4 segs
            int k0g = chunk * 32;
            *(s16x8*)&Bh[c * 40 + seg * 8] = *(const s16x8*)&WT_hi[(size_t)c * 320 + k0g + seg * 8];
            *(s16x8*)&Bl[c * 40 + seg * 8] = *(const s16x8*)&WT_lo[(size_t)c * 320 + k0g + seg * 8];
        }
        __syncthreads();

        s16x8 ah[2], al[2];
#pragma unroll
        for (int mt = 0; mt < 2; ++mt) {
            int r = wm * 32 + mt * 16 + l16;
            ah[mt] = *(s16x8*)&Ah[r * 40 + quad * 8];
            al[mt] = *(s16x8*)&Al[r * 40 + quad * 8];
        }
#pragma unroll
        for (int cg = 0; cg < 2; ++cg) {
            int cc = wn * 32 + cg * 16 + l16;
            s16x8 bh = *(s16x8*)&Bh[cc * 40 + quad * 8];
            s16x8 bl = *(s16x8*)&Bl[cc * 40 + quad * 8];
#pragma unroll
            for (int mt = 0; mt < 2; ++mt) {
                acc[mt][cg] = MFMA(ah[mt], bh, acc[mt][cg]);
                acc[mt][cg] = MFMA(al[mt], bh, acc[mt][cg]);
                acc[mt][cg] = MFMA(ah[mt], bl, acc[mt][cg]);
            }
        }
        __syncthreads();
    }

    // ---- Phase 2: k 64..319 over AGGh (bf16 hi only), all 192 cols ----
    for (int chunk = 0; chunk < 8; ++chunk) {
        {
            int r = t >> 2, seg = t & 3;  // 128 rows x 4 segs
            int row = rows0 + r;
            s16x8 v = (s16x8){0, 0, 0, 0, 0, 0, 0, 0};
            if (row < M) v = *(const s16x8*)&AGGh[(size_t)row * 256 + chunk * 32 + seg * 8];
            *(s16x8*)&Ah[r * 40 + seg * 8] = v;
        }
        {
            int k0g = 64 + chunk * 32;
#pragma unroll
            for (int it = 0; it < 2; ++it) {
                int task = it * 512 + t;  // 192 cols x 4 segs = 768 tasks
                if (task < 768) {
                    int c = task >> 2, seg = task & 3;
                    *(s16x8*)&Bh[c * 40 + seg * 8] = *(const s16x8*)&WT_hi[(size_t)c * 320 + k0g + seg * 8];
                    *(s16x8*)&Bl[c * 40 + seg * 8] = *(const s16x8*)&WT_lo[(size_t)c * 320 + k0g + seg * 8];
                }
            }
        }
        __syncthreads();

        s16x8 ah[2];
#pragma unroll
        for (int mt = 0; mt < 2; ++mt) {
            int r = wm * 32 + mt * 16 + l16;
            ah[mt] = *(s16x8*)&Ah[r * 40 + quad * 8];
        }
#pragma unroll
        for (int tt = 0; tt < 6; ++tt) {
            int cc = wn * 32 + (tt & 1) * 16 + (tt >> 1) * 64 + l16;
            s16x8 bh = *(s16x8*)&Bh[cc * 40 + quad * 8];
            s16x8 bl = *(s16x8*)&Bl[cc * 40 + quad * 8];
#pragma unroll
            for (int mt = 0; mt < 2; ++mt) {
                acc[mt][tt] = MFMA(ah[mt], bh, acc[mt][tt]);
                acc[mt][tt] = MFMA(ah[mt], bl, acc[mt][tt]);
            }
        }
        __syncthreads();
    }

    // epilogue: combine thirds with amp/att, residual + folded bias
#pragma unroll
    for (int mt = 0; mt < 2; ++mt)
#pragma unroll
        for (int cg = 0; cg < 2; ++cg) {
            int col = wn * 32 + cg * 16 + l16;
            float bb = bpp[col];
#pragma unroll
            for (int r = 0; r < 4; ++r) {
                int row = rows0 + wm * 32 + mt * 16 + quad * 4 + r;
                if (row >= M) continue;
                float am = amp[row], at = att[row];
                float v = acc[mt][cg][r] + am * acc[mt][cg + 2][r] + at * acc[mt][cg + 4][r]
                        + hIn[(size_t)row * 64 + col] + bb;
                hOut[(size_t)row * 64 + col] = v;
            }
        }
}

// ---------------- launch ----------------

extern "C" void kernel_launch(void* const* d_in, const int* in_sizes, int n_in,
                              void* d_out, int out_size, void* d_ws, size_t ws_size,
                              hipStream_t stream) {
    const float* x      = (const float*)d_in[0];
    const int*   ei     = (const int*)d_in[1];
    const float* pre_w  = (const float*)d_in[2];
    const float* pre_b  = (const float*)d_in[3];
    const float* post_w = (const float*)d_in[4];
    const float* post_b = (const float*)d_in[5];
    const float* lin_w  = (const float*)d_in[6];
    const float* lin_b  = (const float*)d_in[7];

    const int N = in_sizes[0] / 64;
    const int E = in_sizes[1] / 2;
    const int L = in_sizes[2] / (128 * 64);

    const int* srcIdx = ei;
    const int* dstIdx = ei + E;

    char* ws = (char*)d_ws;
    size_t off = 0;
    auto alloc = [&](size_t bytes) {
        void* p = ws + off;
        off += (bytes + 255) & ~(size_t)255;
        return p;
    };
    int*      deg        = (int*)alloc((size_t)N * 4);
    int*      offs       = (int*)alloc((size_t)(N + 1) * 4);
    u16*      srcSorted  = (u16*)alloc((size_t)E * 2);
    unsigned* edgeTmp    = (unsigned*)alloc((size_t)NBP * CAP * 4);
    int*      part       = (int*)alloc(1024 * 4);
    int*      partOffs   = (int*)alloc(1024 * 4);
    int*      bucketCur  = (int*)alloc(NBP * 4);
    float*    amp        = (float*)alloc((size_t)N * 4);
    float*    att        = (float*)alloc((size_t)N * 4);
    float*    lsum       = (float*)alloc(256);
    u16*      WpT_hi     = (u16*)alloc((size_t)L * 128 * 64 * 2);
    u16*      WpT_lo     = (u16*)alloc((size_t)L * 128 * 64 * 2);
    u16*      WT_hi      = (u16*)alloc((size_t)L * 192 * 320 * 2);
    u16*      WT_lo      = (u16*)alloc((size_t)L * 192 * 320 * 2);
    float*    bpp        = (float*)alloc((size_t)L * 64 * 4);
    u16*      Ph         = (u16*)alloc((size_t)N * 64 * 2);
    u16*      Qh         = (u16*)alloc((size_t)N * 64 * 2);
    u16*      AGGh       = (u16*)alloc((size_t)N * 256 * 2);
    float*    hA         = (float*)alloc((size_t)N * 64 * 4);
    float*    hB         = (float*)alloc((size_t)N * 64 * 4);
    (void)ws_size;

    int G1 = (N + 1023) / 1024;
    int NB = (N + 255) >> 8;          // 256-node buckets (csort blocks)
    int NB1 = (E + EPB2 - 1) / EPB2;  // bucket2 blocks
    int initBlk = (N + 191) / 192;

    k_wprep<<<dim3(449 + initBlk, L), 192, 0, stream>>>(
        pre_w, post_w, post_b, lin_w, lin_b, WpT_hi, WpT_lo, WT_hi, WT_lo, bpp,
        deg, bucketCur, lsum, N);
    k_bucket2<<<NB1, 256, 0, stream>>>(srcIdx, dstIdx, E, deg, bucketCur, edgeTmp);
    k_part<<<G1, 256, 0, stream>>>(deg, N, part, lsum);
    k_scanpart<<<1, 1024, 0, stream>>>(part, G1, E, partOffs, offs, N);
    k_offsets<<<G1, 1024, 0, stream>>>(deg, N, partOffs, lsum, offs, amp, att);
    k_csort<<<NB, 512, 0, stream>>>(edgeTmp, bucketCur, offs, srcSorted, N);

    const float* hIn = x;
    float* hbuf[2] = {hA, hB};
    int gblk = (N + 63) / 64;
    int gblk2 = (N + 127) / 128;
    for (int l = 0; l < L; ++l) {
        float* hOut = (l == L - 1) ? (float*)d_out : hbuf[l & 1];
        k_gemm1<<<gblk, 256, 0, stream>>>(hIn, WpT_hi + (size_t)l * 128 * 64,
                                          WpT_lo + (size_t)l * 128 * 64,
                                          pre_b + (size_t)l * 64, Ph, Qh, N);
        k_agg<<<(N + 7) / 8, 256, 0, stream>>>(Ph, Qh, offs, srcSorted, AGGh, N);
        k_gemm2<<<gblk2, 512, 0, stream>>>(hIn, AGGh,
                                           WT_hi + (size_t)l * 192 * 320,
                                           WT_lo + (size_t)l * 192 * 320,
                                           bpp + (size_t)l * 64,
                                           amp, att, hOut, N);
        hIn = hOut;
    }
}

// Round 13
// 321.815 us; speedup vs baseline: 1.1355x; 1.1355x over previous
//
#include <hip/hip_runtime.h>
#include <math.h>

#define EPSV 1e-5f
#define EPB3 4096  // edges per bucket-pass block (196 blocks)
#define NBP 256    // buckets of 256 nodes (N <= 65536; src packed in 16 bits)
#define CAP 6144   // per-bucket edgeTmp slab capacity (mean ~4081, +32 sigma)

typedef short s16x8 __attribute__((ext_vector_type(8)));
typedef float f32x4 __attribute__((ext_vector_type(4)));
typedef unsigned short u16;

#define MFMA(a, b, c) __builtin_amdgcn_mfma_f32_16x16x32_bf16(a, b, c, 0, 0, 0)

__device__ inline u16 f2bf(float f) {
    unsigned u = __float_as_uint(f);
    return (u16)((u + 0x7FFF + ((u >> 16) & 1)) >> 16);
}
__device__ inline float bf2f(u16 h) { return __uint_as_float(((unsigned)h) << 16); }

__device__ inline void split8(const float4& a, const float4& b, s16x8& hv, s16x8& lv) {
    float f[8] = {a.x, a.y, a.z, a.w, b.x, b.y, b.z, b.w};
#pragma unroll
    for (int i = 0; i < 8; ++i) {
        u16 h = f2bf(f[i]);
        hv[i] = (short)h;
        lv[i] = (short)f2bf(f[i] - bf2f(h));
    }
}

// ---------------- setup kernels ----------------

// merged init + weight prep:
//   bx < 320   : fold WT (post_w @ lin_w, transposed, hi/lo)
//   bx < 448   : pre_w transpose/split
//   bx == 448  : folded bias
//   bx >= 449  : (l==0) zero bucketCur / lsum
__global__ void k_wprep(const float* __restrict__ pre_w, const float* __restrict__ post_w,
                        const float* __restrict__ post_b, const float* __restrict__ lin_w,
                        const float* __restrict__ lin_b, u16* __restrict__ WpT_hi,
                        u16* __restrict__ WpT_lo, u16* __restrict__ WT_hi,
                        u16* __restrict__ WT_lo, float* __restrict__ bpp,
                        int* __restrict__ bucketCur, float* __restrict__ lsum) {
    int l = blockIdx.y, bx = blockIdx.x, t = threadIdx.x;
    if (bx < 320) {
        int k = bx, j = t;  // j<192
        int third = j >> 6, c = j & 63;
        float out = 0.f;
        int r = -1;
        if (k < 64) r = (third == 0) ? k : -1;
        else        r = 64 + third * 256 + (k - 64);
        if (r >= 0) {
            const float* pw = post_w + (size_t)(l * 832 + r) * 64;
            const float* lw = lin_w + (size_t)l * 64 * 64;
            float s = 0.f;
            for (int kk = 0; kk < 64; ++kk) s += pw[kk] * lw[kk * 64 + c];
            out = s;
        }
        u16 h = f2bf(out);
        size_t o = ((size_t)l * 192 + j) * 320 + k;
        WT_hi[o] = h;
        WT_lo[o] = f2bf(out - bf2f(h));
    } else if (bx < 448) {
        if (t < 64) {
            int c = bx - 320, k = t;
            float v = pre_w[(size_t)l * 8192 + (size_t)(k + (c >= 64 ? 64 : 0)) * 64 + (c & 63)];
            u16 h = f2bf(v);
            size_t o = ((size_t)l * 128 + c) * 64 + k;
            WpT_hi[o] = h;
            WpT_lo[o] = f2bf(v - bf2f(h));
        }
    } else if (bx == 448) {
        if (t < 64) {
            int c = t;
            const float* pb = post_b + l * 64;
            const float* lw = lin_w + (size_t)l * 64 * 64;
            float s = lin_b[l * 64 + c];
            for (int k = 0; k < 64; ++k) s += pb[k] * lw[k * 64 + c];
            bpp[l * 64 + c] = s;
        }
    } else if (l == 0) {
        int i = (bx - 449) * 192 + t;
        if (i < NBP) bucketCur[i] = 0;
        if (i == 0) *lsum = 0.f;
    }
}

// bucket partition only (NO deg atomics). LDS-staged: slab writes are
// block-exclusive coalesced runs (~64B). Parallel LDS scan (not serial t0).
// Packed edge word: [bucket:8 | dstLocal:8 | src:16]  (requires N < 65536)
__global__ __launch_bounds__(512) void k_bucket3(const int* __restrict__ src,
                                                 const int* __restrict__ dst, int E,
                                                 int* __restrict__ bucketCursor,
                                                 unsigned* __restrict__ edgeTmp) {
    __shared__ int cnt[NBP], loff[NBP], lpos[NBP], gbase[NBP], sbuf[NBP];
    __shared__ unsigned stage[EPB3];
    int t = threadIdx.x;
    int base = blockIdx.x * EPB3;
    int cntE = min(EPB3, E - base);
    if (t < NBP) cnt[t] = 0;
    __syncthreads();
    unsigned ed[8];
#pragma unroll
    for (int j = 0; j < 8; ++j) {
        int idx = j * 512 + t;
        if (idx < cntE) {
            int e = base + idx;
            unsigned s = (unsigned)src[e];
            unsigned d = (unsigned)dst[e];
            ed[j] = ((d >> 8) << 24) | ((d & 255u) << 16) | s;
            atomicAdd(&cnt[d >> 8], 1);
        } else ed[j] = 0xFFFFFFFFu;
    }
    __syncthreads();
    // parallel exclusive scan of cnt -> loff
    if (t < NBP) sbuf[t] = cnt[t];
    __syncthreads();
    for (int o = 1; o < NBP; o <<= 1) {
        int v = 0;
        if (t < NBP && t >= o) v = sbuf[t - o];
        __syncthreads();
        if (t < NBP) sbuf[t] += v;
        __syncthreads();
    }
    if (t < NBP) {
        loff[t] = sbuf[t] - cnt[t];
        lpos[t] = sbuf[t] - cnt[t];
        gbase[t] = (cnt[t] > 0) ? atomicAdd(&bucketCursor[t], cnt[t]) : 0;
    }
    __syncthreads();
#pragma unroll
    for (int j = 0; j < 8; ++j) {
        if (ed[j] != 0xFFFFFFFFu) {
            int b = ed[j] >> 24;
            int p = atomicAdd(&lpos[b], 1);
            stage[p] = ed[j];
        }
    }
    __syncthreads();
    for (int i = t; i < cntE; i += 512) {
        unsigned pr = stage[i];
        int b = pr >> 24;
        int pos = gbase[b] + (i - loff[b]);
        if (pos < CAP) edgeTmp[(size_t)b * CAP + pos] = pr;
    }
}

// counting-sort each 256-node bucket slab; also produces deg[], offs[], and
// the global log-degree sum (absorbs the old k_deg/k_part/k_scanpart/k_offsets).
__global__ __launch_bounds__(512) void k_csort2(const unsigned* __restrict__ edgeTmp,
                                                const int* __restrict__ bucketCur,
                                                int* __restrict__ deg,
                                                int* __restrict__ offs,
                                                float* __restrict__ lsum,
                                                u16* __restrict__ srcSorted,
                                                int N, int E, int NB) {
    __shared__ int bcnt[NBP], sbuf[NBP], lcur[NBP], lofs[NBP];
    __shared__ float fred[256];
    __shared__ u16 stageSrc[CAP];
    __shared__ int e0s;
    int b = blockIdx.x, t = threadIdx.x;
    int n0 = b << 8;
    int nodes = min(256, N - n0);
    // global base for this bucket = sum of bucket counts below b
    if (t < NBP) bcnt[t] = (t < NB) ? bucketCur[t] : 0;
    if (t < NBP) lcur[t] = 0;
    __syncthreads();
    if (t < NBP) sbuf[t] = bcnt[t];
    __syncthreads();
    for (int o = 1; o < NBP; o <<= 1) {
        int v = 0;
        if (t < NBP && t >= o) v = sbuf[t - o];
        __syncthreads();
        if (t < NBP) sbuf[t] += v;
        __syncthreads();
    }
    if (t == 0) e0s = sbuf[b] - bcnt[b];
    __syncthreads();
    int e0 = e0s;
    int cnt = min(bcnt[b], CAP);
    const unsigned* ebase = edgeTmp + (size_t)b * CAP;
    // phase A: per-node counts
    for (int i = t; i < cnt; i += 512) atomicAdd(&lcur[(ebase[i] >> 16) & 255], 1);
    __syncthreads();
    // deg + log-sum
    float ls = 0.f;
    if (t < 256) {
        if (t < nodes) {
            int d = lcur[t];
            deg[n0 + t] = d;
            ls = logf(fmaxf((float)d, 1.f) + 1.f);
        }
        fred[t] = ls;
    }
    // exclusive scan of lcur -> lofs
    if (t < NBP) sbuf[t] = lcur[t];
    __syncthreads();
    for (int o = 1; o < NBP; o <<= 1) {
        int v = 0;
        if (t < NBP && t >= o) v = sbuf[t - o];
        __syncthreads();
        if (t < NBP) sbuf[t] += v;
        __syncthreads();
    }
    if (t < NBP) lofs[t] = sbuf[t] - lcur[t];
    if (t < nodes) offs[n0 + t] = e0 + (sbuf[t] - lcur[t]);
    if (b == 0 && t == 0) offs[N] = E;
    // reduce fred -> lsum
    __syncthreads();
    for (int o = 128; o > 0; o >>= 1) {
        if (t < o) fred[t] += fred[t + o];
        __syncthreads();
    }
    if (t == 0) atomicAdd(lsum, fred[0]);
    // phase B: place (reuse sbuf as cursor)
    if (t < NBP) sbuf[t] = 0;
    __syncthreads();
    for (int i = t; i < cnt; i += 512) {
        unsigned p = ebase[i];
        int dl = (p >> 16) & 255;
        int r = atomicAdd(&sbuf[dl], 1);
        stageSrc[lofs[dl] + r] = (u16)(p & 0xFFFFu);
    }
    __syncthreads();
    for (int i = t; i < cnt; i += 512) srcSorted[e0 + i] = stageSrc[i];
}

__global__ void k_scalers(const int* __restrict__ deg, int N,
                          const float* __restrict__ lsum,
                          float* __restrict__ amp, float* __restrict__ att) {
    int i = blockIdx.x * 256 + threadIdx.x;
    if (i >= N) return;
    float dc = fmaxf((float)deg[i], 1.f);
    float ld = logf(dc + 1.f);
    float avg = *lsum / (float)N;
    amp[i] = ld / avg;
    att[i] = avg / ld;
}

// ---------------- per-layer kernels (unchanged, proven round 11) ----------------

__global__ __launch_bounds__(256) void k_gemm1(const float* __restrict__ h,
                                               const u16* __restrict__ WpT_hi,
                                               const u16* __restrict__ WpT_lo,
                                               const float* __restrict__ pre_b,
                                               u16* __restrict__ Ph, u16* __restrict__ Qh,
                                               int M) {
    __shared__ u16 Ah[64 * 72], Al[64 * 72];
    __shared__ u16 Bh[128 * 72], Bl[128 * 72];
    int t = threadIdx.x, wid = t >> 6, lane = t & 63;
    int rows0 = blockIdx.x * 64;
    int quad = lane >> 4, l16 = lane & 15;
    int wm = wid & 1, wn = wid >> 1;

#pragma unroll
    for (int it = 0; it < 2; ++it) {
        int task = it * 256 + t;
        int r = task >> 3, seg = task & 7;
        int row = rows0 + r;
        float4 v0 = make_float4(0.f, 0.f, 0.f, 0.f), v1 = v0;
        if (row < M) {
            v0 = *(const float4*)&h[(size_t)row * 64 + seg * 8];
            v1 = *(const float4*)&h[(size_t)row * 64 + seg * 8 + 4];
        }
        s16x8 hv, lv;
        split8(v0, v1, hv, lv);
        *(s16x8*)&Ah[r * 72 + seg * 8] = hv;
        *(s16x8*)&Al[r * 72 + seg * 8] = lv;
    }
#pragma unroll
    for (int it = 0; it < 4; ++it) {
        int task = it * 256 + t;
        int c = task >> 3, seg = task & 7;
        *(s16x8*)&Bh[c * 72 + seg * 8] = *(const s16x8*)&WpT_hi[(size_t)c * 64 + seg * 8];
        *(s16x8*)&Bl[c * 72 + seg * 8] = *(const s16x8*)&WpT_lo[(size_t)c * 64 + seg * 8];
    }
    __syncthreads();

    f32x4 acc[2][4];
#pragma unroll
    for (int mt = 0; mt < 2; ++mt)
#pragma unroll
        for (int tt = 0; tt < 4; ++tt) acc[mt][tt] = (f32x4){0.f, 0.f, 0.f, 0.f};

#pragma unroll
    for (int c = 0; c < 2; ++c) {
        s16x8 ah[2], al[2];
#pragma unroll
        for (int mt = 0; mt < 2; ++mt) {
            int r = wm * 32 + mt * 16 + l16;
            ah[mt] = *(s16x8*)&Ah[r * 72 + c * 32 + quad * 8];
            al[mt] = *(s16x8*)&Al[r * 72 + c * 32 + quad * 8];
        }
#pragma unroll
        for (int tt = 0; tt < 4; ++tt) {
            int cc = wn * 64 + tt * 16 + l16;
            s16x8 bh = *(s16x8*)&Bh[cc * 72 + c * 32 + quad * 8];
            s16x8 bl = *(s16x8*)&Bl[cc * 72 + c * 32 + quad * 8];
#pragma unroll
            for (int mt = 0; mt < 2; ++mt) {
                acc[mt][tt] = MFMA(ah[mt], bh, acc[mt][tt]);
                acc[mt][tt] = MFMA(ah[mt], bl, acc[mt][tt]);
                if (wn == 0) acc[mt][tt] = MFMA(al[mt], bh, acc[mt][tt]);
            }
        }
    }

#pragma unroll
    for (int mt = 0; mt < 2; ++mt)
#pragma unroll
        for (int tt = 0; tt < 4; ++tt) {
            int col = wn * 64 + tt * 16 + l16;
#pragma unroll
            for (int r = 0; r < 4; ++r) {
                int row = rows0 + wm * 32 + mt * 16 + quad * 4 + r;
                if (row >= M) continue;
                float v = acc[mt][tt][r];
                if (col < 64) Ph[(size_t)row * 64 + col] = f2bf(v + pre_b[col]);
                else          Qh[(size_t)row * 64 + (col - 64)] = f2bf(v);
            }
        }
}

// aggregation: one wave handles TWO nodes, each 8-deep unrolled
// -> 16 independent gathers in flight; lane = feature.
__global__ __launch_bounds__(256) void k_agg(const u16* __restrict__ Ph,
                                             const u16* __restrict__ Qh,
                                             const int* __restrict__ offs,
                                             const u16* __restrict__ ss,
                                             u16* __restrict__ AGGh, int N) {
    int w = threadIdx.x >> 6, lane = threadIdx.x & 63;
    int i0 = blockIdx.x * 8 + w * 2;
    int i1 = i0 + 1;
    if (i0 >= N) return;
    int beg0 = offs[i0], end0 = offs[i0 + 1];
    int beg1 = 0, end1 = 0;
    if (i1 < N) { beg1 = offs[i1]; end1 = offs[i1 + 1]; }
    float sum0 = 0.f, sqa0 = 0.f, sqb0 = 0.f, mx0 = -3.4e38f, mn0 = 3.4e38f;
    float sum1 = 0.f, sqa1 = 0.f, sqb1 = 0.f, mx1 = -3.4e38f, mn1 = 3.4e38f;
    int e0 = beg0, e1 = beg1;
    while (e0 + 8 <= end0 && e1 + 8 <= end1) {
        float qa[8], qb[8];
#pragma unroll
        for (int j = 0; j < 8; ++j) qa[j] = bf2f(Qh[((int)ss[e0 + j] << 6) + lane]);
#pragma unroll
        for (int j = 0; j < 8; ++j) qb[j] = bf2f(Qh[((int)ss[e1 + j] << 6) + lane]);
        sum0 += ((qa[0] + qa[1]) + (qa[2] + qa[3])) + ((qa[4] + qa[5]) + (qa[6] + qa[7]));
        sqa0 = fmaf(qa[0], qa[0], fmaf(qa[2], qa[2], fmaf(qa[4], qa[4], fmaf(qa[6], qa[6], sqa0))));
        sqb0 = fmaf(qa[1], qa[1], fmaf(qa[3], qa[3], fmaf(qa[5], qa[5], fmaf(qa[7], qa[7], sqb0))));
        mx0 = fmaxf(mx0, fmaxf(fmaxf(fmaxf(qa[0], qa[1]), fmaxf(qa[2], qa[3])),
                               fmaxf(fmaxf(qa[4], qa[5]), fmaxf(qa[6], qa[7]))));
        mn0 = fminf(mn0, fminf(fminf(fminf(qa[0], qa[1]), fminf(qa[2], qa[3])),
                               fminf(fminf(qa[4], qa[5]), fminf(qa[6], qa[7]))));
        sum1 += ((qb[0] + qb[1]) + (qb[2] + qb[3])) + ((qb[4] + qb[5]) + (qb[6] + qb[7]));
        sqa1 = fmaf(qb[0], qb[0], fmaf(qb[2], qb[2], fmaf(qb[4], qb[4], fmaf(qb[6], qb[6], sqa1))));
        sqb1 = fmaf(qb[1], qb[1], fmaf(qb[3], qb[3], fmaf(qb[5], qb[5], fmaf(qb[7], qb[7], sqb1))));
        mx1 = fmaxf(mx1, fmaxf(fmaxf(fmaxf(qb[0], qb[1]), fmaxf(qb[2], qb[3])),
                               fmaxf(fmaxf(qb[4], qb[5]), fmaxf(qb[6], qb[7]))));
        mn1 = fminf(mn1, fminf(fminf(fminf(qb[0], qb[1]), fminf(qb[2], qb[3])),
                               fminf(fminf(qb[4], qb[5]), fminf(qb[6], qb[7]))));
        e0 += 8; e1 += 8;
    }
    for (; e0 + 4 <= end0; e0 += 4) {
        float q0 = bf2f(Qh[((int)ss[e0 + 0] << 6) + lane]);
        float q1 = bf2f(Qh[((int)ss[e0 + 1] << 6) + lane]);
        float q2 = bf2f(Qh[((int)ss[e0 + 2] << 6) + lane]);
        float q3 = bf2f(Qh[((int)ss[e0 + 3] << 6) + lane]);
        sum0 += (q0 + q1) + (q2 + q3);
        sqa0 = fmaf(q0, q0, fmaf(q2, q2, sqa0));
        sqb0 = fmaf(q1, q1, fmaf(q3, q3, sqb0));
        mx0 = fmaxf(mx0, fmaxf(fmaxf(q0, q1), fmaxf(q2, q3)));
        mn0 = fminf(mn0, fminf(fminf(q0, q1), fminf(q2, q3)));
    }
    for (; e1 + 4 <= end1; e1 += 4) {
        float q0 = bf2f(Qh[((int)ss[e1 + 0] << 6) + lane]);
        float q1 = bf2f(Qh[((int)ss[e1 + 1] << 6) + lane]);
        float q2 = bf2f(Qh[((int)ss[e1 + 2] << 6) + lane]);
        float q3 = bf2f(Qh[((int)ss[e1 + 3] << 6) + lane]);
        sum1 += (q0 + q1) + (q2 + q3);
        sqa1 = fmaf(q0, q0, fmaf(q2, q2, sqa1));
        sqb1 = fmaf(q1, q1, fmaf(q3, q3, sqb1));
        mx1 = fmaxf(mx1, fmaxf(fmaxf(q0, q1), fmaxf(q2, q3)));
        mn1 = fminf(mn1, fminf(fminf(q0, q1), fminf(q2, q3)));
    }
    for (; e0 < end0; ++e0) {
        float q = bf2f(Qh[((int)ss[e0] << 6) + lane]);
        sum0 += q; sqa0 = fmaf(q, q, sqa0);
        mx0 = fmaxf(mx0, q); mn0 = fminf(mn0, q);
    }
    for (; e1 < end1; ++e1) {
        float q = bf2f(Qh[((int)ss[e1] << 6) + lane]);
        sum1 += q; sqa1 = fmaf(q, q, sqa1);
        mx1 = fmaxf(mx1, q); mn1 = fminf(mn1, q);
    }
    {
        int deg = end0 - beg0;
        float sq = sqa0 + sqb0;
        float p = bf2f(Ph[(i0 << 6) + lane]);
        float dc = fmaxf((float)deg, 1.f);
        float eq = sum0 / dc;
        float var = fmaxf(sq / dc - eq * eq, 0.f);
        float sd = sqrtf(var + EPSV);
        float mean, vmx, vmn;
        if (deg > 0) { mean = p + eq; vmx = p + mx0; vmn = p + mn0; }
        else         { mean = 0.f; vmx = 0.f; vmn = 0.f; }
        int o = (i0 << 8) + lane;
        AGGh[o] = f2bf(mean);
        AGGh[o + 64] = f2bf(vmx);
        AGGh[o + 128] = f2bf(vmn);
        AGGh[o + 192] = f2bf(sd);
    }
    if (i1 < N) {
        int deg = end1 - beg1;
        float sq = sqa1 + sqb1;
        float p = bf2f(Ph[(i1 << 6) + lane]);
        float dc = fmaxf((float)deg, 1.f);
        float eq = sum1 / dc;
        float var = fmaxf(sq / dc - eq * eq, 0.f);
        float sd = sqrtf(var + EPSV);
        float mean, vmx, vmn;
        if (deg > 0) { mean = p + eq; vmx = p + mx1; vmn = p + mn1; }
        else         { mean = 0.f; vmx = 0.f; vmn = 0.f; }
        int o = (i1 << 8) + lane;
        AGGh[o] = f2bf(mean);
        AGGh[o + 64] = f2bf(vmx);
        AGGh[o + 128] = f2bf(vmn);
        AGGh[o + 192] = f2bf(sd);
    }
}

// gemm2: 128-row blocks, 512 threads (8 waves).
__global__ __launch_bounds__(512) void k_gemm2(const float* __restrict__ hIn,
                                               const u16* __restrict__ AGGh,
                                               const u16* __restrict__ WT_hi,
                                               const u16* __restrict__ WT_lo,
                                               const float* __restrict__ bpp,
                                               const float* __restrict__ amp,
                                               const float* __restrict__ att,
                                               float* __restrict__ hOut, int M) {
    __shared__ u16 Ah[128 * 40], Al[128 * 40];  // [row][k-chunk 32], pitch 40
    __shared__ u16 Bh[192 * 40], Bl[192 * 40];  // [col][k-chunk 32], pitch 40
    int t = threadIdx.x, wid = t >> 6, lane = t & 63;
    int rows0 = blockIdx.x * 128;
    int quad = lane >> 4, l16 = lane & 15;
    int wm = wid & 3, wn = wid >> 2;

    f32x4 acc[2][6];  // [mt][cg + third*2]
#pragma unroll
    for (int mt = 0; mt < 2; ++mt)
#pragma unroll
        for (int tt = 0; tt < 6; ++tt) acc[mt][tt] = (f32x4){0.f, 0.f, 0.f, 0.f};

    // ---- Phase 1: k 0..63 over hIn (hi/lo split), cols 0:64 only ----
#pragma unroll
    for (int chunk = 0; chunk < 2; ++chunk) {
        {
            int r = t >> 2, seg = t & 3;  // 128 rows x 4 segs = 512 tasks
            int row = rows0 + r;
            float4 v0 = make_float4(0.f, 0.f, 0.f, 0.f), v1 = v0;
            if (row < M) {
                v0 = *(const float4*)&hIn[(size_t)row * 64 + chunk * 32 + seg * 8];
                v1 = *(const float4*)&hIn[(size_t)row * 64 + chunk * 32 + seg * 8 + 4];
            }
            s16x8 hv, lv;
            split8(v0, v1, hv, lv);
            *(s16x8*)&Ah[r * 40 + seg * 8] = hv;
            *(s16x8*)&Al[r * 40 + seg * 8] = lv;
        }
        if (t < 256) {
            int c = t >> 2, seg = t & 3;  // 64 cols x 4 segs
            int k0g = chunk * 32;
            *(s16x8*)&Bh[c * 40 + seg * 8] = *(const s16x8*)&WT_hi[(size_t)c * 320 + k0g + seg * 8];
            *(s16x8*)&Bl[c * 40 + seg * 8] = *(const s16x8*)&WT_lo[(size_t)c * 320 + k0g + seg * 8];
        }
        __syncthreads();

        s16x8 ah[2], al[2];
#pragma unroll
        for (int mt = 0; mt < 2; ++mt) {
            int r = wm * 32 + mt * 16 + l16;
            ah[mt] = *(s16x8*)&Ah[r * 40 + quad * 8];
            al[mt] = *(s16x8*)&Al[r * 40 + quad * 8];
        }
#pragma unroll
        for (int cg = 0; cg < 2; ++cg) {
            int cc = wn * 32 + cg * 16 + l16;
            s16x8 bh = *(s16x8*)&Bh[cc * 40 + quad * 8];
            s16x8 bl = *(s16x8*)&Bl[cc * 40 + quad * 8];
#pragma unroll
            for (int mt = 0; mt < 2; ++mt) {
                acc[mt][cg] = MFMA(ah[mt], bh, acc[mt][cg]);
                acc[mt][cg] = MFMA(al[mt], bh, acc[mt][cg]);
                acc[mt][cg] = MFMA(ah[mt], bl, acc[mt][cg]);
            }
        }
        __syncthreads();
    }

    // ---- Phase 2: k 64..319 over AGGh (bf16 hi only), all 192 cols ----
    for (int chunk = 0; chunk < 8; ++chunk) {
        {
            int r = t >> 2, seg = t & 3;  // 128 rows x 4 segs
            int row = rows0 + r;
            s16x8 v = (s16x8){0, 0, 0, 0, 0, 0, 0, 0};
            if (row < M) v = *(const s16x8*)&AGGh[(size_t)row * 256 + chunk * 32 + seg * 8];
            *(s16x8*)&Ah[r * 40 + seg * 8] = v;
        }
        {
            int k0g = 64 + chunk * 32;
#pragma unroll
            for (int it = 0; it < 2; ++it) {
                int task = it * 512 + t;  // 192 cols x 4 segs = 768 tasks
                if (task < 768) {
                    int c = task >> 2, seg = task & 3;
                    *(s16x8*)&Bh[c * 40 + seg * 8] = *(const s16x8*)&WT_hi[(size_t)c * 320 + k0g + seg * 8];
                    *(s16x8*)&Bl[c * 40 + seg * 8] = *(const s16x8*)&WT_lo[(size_t)c * 320 + k0g + seg * 8];
                }
            }
        }
        __syncthreads();

        s16x8 ah[2];
#pragma unroll
        for (int mt = 0; mt < 2; ++mt) {
            int r = wm * 32 + mt * 16 + l16;
            ah[mt] = *(s16x8*)&Ah[r * 40 + quad * 8];
        }
#pragma unroll
        for (int tt = 0; tt < 6; ++tt) {
            int cc = wn * 32 + (tt & 1) * 16 + (tt >> 1) * 64 + l16;
            s16x8 bh = *(s16x8*)&Bh[cc * 40 + quad * 8];
            s16x8 bl = *(s16x8*)&Bl[cc * 40 + quad * 8];
#pragma unroll
            for (int mt = 0; mt < 2; ++mt) {
                acc[mt][tt] = MFMA(ah[mt], bh, acc[mt][tt]);
                acc[mt][tt] = MFMA(ah[mt], bl, acc[mt][tt]);
            }
        }
        __syncthreads();
    }

    // epilogue: combine thirds with amp/att, residual + folded bias
#pragma unroll
    for (int mt = 0; mt < 2; ++mt)
#pragma unroll
        for (int cg = 0; cg < 2; ++cg) {
            int col = wn * 32 + cg * 16 + l16;
            float bb = bpp[col];
#pragma unroll
            for (int r = 0; r < 4; ++r) {
                int row = rows0 + wm * 32 + mt * 16 + quad * 4 + r;
                if (row >= M) continue;
                float am = amp[row], at = att[row];
                float v = acc[mt][cg][r] + am * acc[mt][cg + 2][r] + at * acc[mt][cg + 4][r]
                        + hIn[(size_t)row * 64 + col] + bb;
                hOut[(size_t)row * 64 + col] = v;
            }
        }
}

// ---------------- launch ----------------

extern "C" void kernel_launch(void* const* d_in, const int* in_sizes, int n_in,
                              void* d_out, int out_size, void* d_ws, size_t ws_size,
                              hipStream_t stream) {
    const float* x      = (const float*)d_in[0];
    const int*   ei     = (const int*)d_in[1];
    const float* pre_w  = (const float*)d_in[2];
    const float* pre_b  = (const float*)d_in[3];
    const float* post_w = (const float*)d_in[4];
    const float* post_b = (const float*)d_in[5];
    const float* lin_w  = (const float*)d_in[6];
    const float* lin_b  = (const float*)d_in[7];

    const int N = in_sizes[0] / 64;
    const int E = in_sizes[1] / 2;
    const int L = in_sizes[2] / (128 * 64);

    const int* srcIdx = ei;
    const int* dstIdx = ei + E;

    char* ws = (char*)d_ws;
    size_t off = 0;
    auto alloc = [&](size_t bytes) {
        void* p = ws + off;
        off += (bytes + 255) & ~(size_t)255;
        return p;
    };
    int*      deg        = (int*)alloc((size_t)N * 4);
    int*      offs       = (int*)alloc((size_t)(N + 1) * 4);
    u16*      srcSorted  = (u16*)alloc((size_t)E * 2);
    unsigned* edgeTmp    = (unsigned*)alloc((size_t)NBP * CAP * 4);
    int*      bucketCur  = (int*)alloc(NBP * 4);
    float*    amp        = (float*)alloc((size_t)N * 4);
    float*    att        = (float*)alloc((size_t)N * 4);
    float*    lsum       = (float*)alloc(256);
    u16*      WpT_hi     = (u16*)alloc((size_t)L * 128 * 64 * 2);
    u16*      WpT_lo     = (u16*)alloc((size_t)L * 128 * 64 * 2);
    u16*      WT_hi      = (u16*)alloc((size_t)L * 192 * 320 * 2);
    u16*      WT_lo      = (u16*)alloc((size_t)L * 192 * 320 * 2);
    float*    bpp        = (float*)alloc((size_t)L * 64 * 4);
    u16*      Ph         = (u16*)alloc((size_t)N * 64 * 2);
    u16*      Qh         = (u16*)alloc((size_t)N * 64 * 2);
    u16*      AGGh       = (u16*)alloc((size_t)N * 256 * 2);
    float*    hA         = (float*)alloc((size_t)N * 64 * 4);
    float*    hB         = (float*)alloc((size_t)N * 64 * 4);
    (void)ws_size;

    int NB = (N + 255) >> 8;          // 256-node buckets (csort blocks)
    int NB1 = (E + EPB3 - 1) / EPB3;  // bucket3 blocks
    int initBlk = (NBP + 191) / 192;  // zero bucketCur/lsum

    k_wprep<<<dim3(449 + initBlk, L), 192, 0, stream>>>(
        pre_w, post_w, post_b, lin_w, lin_b, WpT_hi, WpT_lo, WT_hi, WT_lo, bpp,
        bucketCur, lsum);
    k_bucket3<<<NB1, 512, 0, stream>>>(srcIdx, dstIdx, E, bucketCur, edgeTmp);
    k_csort2<<<NB, 512, 0, stream>>>(edgeTmp, bucketCur, deg, offs, lsum,
                                     srcSorted, N, E, NB);
    k_scalers<<<(N + 255) / 256, 256, 0, stream>>>(deg, N, lsum, amp, att);

    const float* hIn = x;
    float* hbuf[2] = {hA, hB};
    int gblk = (N + 63) / 64;
    int gblk2 = (N + 127) / 128;
    for (int l = 0; l < L; ++l) {
        float* hOut = (l == L - 1) ? (float*)d_out : hbuf[l & 1];
        k_gemm1<<<gblk, 256, 0, stream>>>(hIn, WpT_hi + (size_t)l * 128 * 64,
                                          WpT_lo + (size_t)l * 128 * 64,
                                          pre_b + (size_t)l * 64, Ph, Qh, N);
        k_agg<<<(N + 7) / 8, 256, 0, stream>>>(Ph, Qh, offs, srcSorted, AGGh, N);
        k_gemm2<<<gblk2, 512, 0, stream>>>(hIn, AGGh,
                                           WT_hi + (size_t)l * 192 * 320,
                                           WT_lo + (size_t)l * 192 * 320,
                                           bpp + (size_t)l * 64,
                                           amp, att, hOut, N);
        hIn = hOut;
    }
}

// Round 14
// 306.154 us; speedup vs baseline: 1.1936x; 1.0512x over previous
//
#include <hip/hip_runtime.h>
#include <math.h>

#define EPSV 1e-5f
#define EPB3 4096  // edges per bucket-pass block (196 blocks)
#define NBP 256    // buckets of 256 nodes (N <= 65536; src packed in 16 bits)
#define CAP 6144   // per-bucket edgeTmp slab capacity (mean ~4081, +32 sigma)

typedef short s16x8 __attribute__((ext_vector_type(8)));
typedef float f32x4 __attribute__((ext_vector_type(4)));
typedef unsigned short u16;

#define MFMA(a, b, c) __builtin_amdgcn_mfma_f32_16x16x32_bf16(a, b, c, 0, 0, 0)

__device__ inline u16 f2bf(float f) {
    unsigned u = __float_as_uint(f);
    return (u16)((u + 0x7FFF + ((u >> 16) & 1)) >> 16);
}
__device__ inline float bf2f(u16 h) { return __uint_as_float(((unsigned)h) << 16); }

__device__ inline void split8(const float4& a, const float4& b, s16x8& hv, s16x8& lv) {
    float f[8] = {a.x, a.y, a.z, a.w, b.x, b.y, b.z, b.w};
#pragma unroll
    for (int i = 0; i < 8; ++i) {
        u16 h = f2bf(f[i]);
        hv[i] = (short)h;
        lv[i] = (short)f2bf(f[i] - bf2f(h));
    }
}

// ---------------- setup kernels (proven round 13) ----------------

__global__ void k_wprep(const float* __restrict__ pre_w, const float* __restrict__ post_w,
                        const float* __restrict__ post_b, const float* __restrict__ lin_w,
                        const float* __restrict__ lin_b, u16* __restrict__ WpT_hi,
                        u16* __restrict__ WpT_lo, u16* __restrict__ WT_hi,
                        u16* __restrict__ WT_lo, float* __restrict__ bpp,
                        int* __restrict__ bucketCur, float* __restrict__ lsum) {
    int l = blockIdx.y, bx = blockIdx.x, t = threadIdx.x;
    if (bx < 320) {
        int k = bx, j = t;  // j<192
        int third = j >> 6, c = j & 63;
        float out = 0.f;
        int r = -1;
        if (k < 64) r = (third == 0) ? k : -1;
        else        r = 64 + third * 256 + (k - 64);
        if (r >= 0) {
            const float* pw = post_w + (size_t)(l * 832 + r) * 64;
            const float* lw = lin_w + (size_t)l * 64 * 64;
            float s = 0.f;
            for (int kk = 0; kk < 64; ++kk) s += pw[kk] * lw[kk * 64 + c];
            out = s;
        }
        u16 h = f2bf(out);
        size_t o = ((size_t)l * 192 + j) * 320 + k;
        WT_hi[o] = h;
        WT_lo[o] = f2bf(out - bf2f(h));
    } else if (bx < 448) {
        if (t < 64) {
            int c = bx - 320, k = t;
            float v = pre_w[(size_t)l * 8192 + (size_t)(k + (c >= 64 ? 64 : 0)) * 64 + (c & 63)];
            u16 h = f2bf(v);
            size_t o = ((size_t)l * 128 + c) * 64 + k;
            WpT_hi[o] = h;
            WpT_lo[o] = f2bf(v - bf2f(h));
        }
    } else if (bx == 448) {
        if (t < 64) {
            int c = t;
            const float* pb = post_b + l * 64;
            const float* lw = lin_w + (size_t)l * 64 * 64;
            float s = lin_b[l * 64 + c];
            for (int k = 0; k < 64; ++k) s += pb[k] * lw[k * 64 + c];
            bpp[l * 64 + c] = s;
        }
    } else if (l == 0) {
        int i = (bx - 449) * 192 + t;
        if (i < NBP) bucketCur[i] = 0;
        if (i == 0) *lsum = 0.f;
    }
}

// bucket partition (no deg atomics), LDS-staged coalesced slab writes.
// Packed edge word: [bucket:8 | dstLocal:8 | src:16]
__global__ __launch_bounds__(512) void k_bucket3(const int* __restrict__ src,
                                                 const int* __restrict__ dst, int E,
                                                 int* __restrict__ bucketCursor,
                                                 unsigned* __restrict__ edgeTmp) {
    __shared__ int cnt[NBP], loff[NBP], lpos[NBP], gbase[NBP], sbuf[NBP];
    __shared__ unsigned stage[EPB3];
    int t = threadIdx.x;
    int base = blockIdx.x * EPB3;
    int cntE = min(EPB3, E - base);
    if (t < NBP) cnt[t] = 0;
    __syncthreads();
    unsigned ed[8];
#pragma unroll
    for (int j = 0; j < 8; ++j) {
        int idx = j * 512 + t;
        if (idx < cntE) {
            int e = base + idx;
            unsigned s = (unsigned)src[e];
            unsigned d = (unsigned)dst[e];
            ed[j] = ((d >> 8) << 24) | ((d & 255u) << 16) | s;
            atomicAdd(&cnt[d >> 8], 1);
        } else ed[j] = 0xFFFFFFFFu;
    }
    __syncthreads();
    if (t < NBP) sbuf[t] = cnt[t];
    __syncthreads();
    for (int o = 1; o < NBP; o <<= 1) {
        int v = 0;
        if (t < NBP && t >= o) v = sbuf[t - o];
        __syncthreads();
        if (t < NBP) sbuf[t] += v;
        __syncthreads();
    }
    if (t < NBP) {
        loff[t] = sbuf[t] - cnt[t];
        lpos[t] = sbuf[t] - cnt[t];
        gbase[t] = (cnt[t] > 0) ? atomicAdd(&bucketCursor[t], cnt[t]) : 0;
    }
    __syncthreads();
#pragma unroll
    for (int j = 0; j < 8; ++j) {
        if (ed[j] != 0xFFFFFFFFu) {
            int b = ed[j] >> 24;
            int p = atomicAdd(&lpos[b], 1);
            stage[p] = ed[j];
        }
    }
    __syncthreads();
    for (int i = t; i < cntE; i += 512) {
        unsigned pr = stage[i];
        int b = pr >> 24;
        int pos = gbase[b] + (i - loff[b]);
        if (pos < CAP) edgeTmp[(size_t)b * CAP + pos] = pr;
    }
}

// counting-sort each bucket slab; produces deg[], offs[], lsum, srcSorted.
__global__ __launch_bounds__(512) void k_csort2(const unsigned* __restrict__ edgeTmp,
                                                const int* __restrict__ bucketCur,
                                                int* __restrict__ deg,
                                                int* __restrict__ offs,
                                                float* __restrict__ lsum,
                                                u16* __restrict__ srcSorted,
                                                int N, int E, int NB) {
    __shared__ int bcnt[NBP], sbuf[NBP], lcur[NBP], lofs[NBP];
    __shared__ float fred[256];
    __shared__ u16 stageSrc[CAP];
    __shared__ int e0s;
    int b = blockIdx.x, t = threadIdx.x;
    int n0 = b << 8;
    int nodes = min(256, N - n0);
    if (t < NBP) bcnt[t] = (t < NB) ? bucketCur[t] : 0;
    if (t < NBP) lcur[t] = 0;
    __syncthreads();
    if (t < NBP) sbuf[t] = bcnt[t];
    __syncthreads();
    for (int o = 1; o < NBP; o <<= 1) {
        int v = 0;
        if (t < NBP && t >= o) v = sbuf[t - o];
        __syncthreads();
        if (t < NBP) sbuf[t] += v;
        __syncthreads();
    }
    if (t == 0) e0s = sbuf[b] - bcnt[b];
    __syncthreads();
    int e0 = e0s;
    int cnt = min(bcnt[b], CAP);
    const unsigned* ebase = edgeTmp + (size_t)b * CAP;
    for (int i = t; i < cnt; i += 512) atomicAdd(&lcur[(ebase[i] >> 16) & 255], 1);
    __syncthreads();
    float ls = 0.f;
    if (t < 256) {
        if (t < nodes) {
            int d = lcur[t];
            deg[n0 + t] = d;
            ls = logf(fmaxf((float)d, 1.f) + 1.f);
        }
        fred[t] = ls;
    }
    if (t < NBP) sbuf[t] = lcur[t];
    __syncthreads();
    for (int o = 1; o < NBP; o <<= 1) {
        int v = 0;
        if (t < NBP && t >= o) v = sbuf[t - o];
        __syncthreads();
        if (t < NBP) sbuf[t] += v;
        __syncthreads();
    }
    if (t < NBP) lofs[t] = sbuf[t] - lcur[t];
    if (t < nodes) offs[n0 + t] = e0 + (sbuf[t] - lcur[t]);
    if (b == 0 && t == 0) offs[N] = E;
    __syncthreads();
    for (int o = 128; o > 0; o >>= 1) {
        if (t < o) fred[t] += fred[t + o];
        __syncthreads();
    }
    if (t == 0) atomicAdd(lsum, fred[0]);
    if (t < NBP) sbuf[t] = 0;
    __syncthreads();
    for (int i = t; i < cnt; i += 512) {
        unsigned p = ebase[i];
        int dl = (p >> 16) & 255;
        int r = atomicAdd(&sbuf[dl], 1);
        stageSrc[lofs[dl] + r] = (u16)(p & 0xFFFFu);
    }
    __syncthreads();
    for (int i = t; i < cnt; i += 512) srcSorted[e0 + i] = stageSrc[i];
}

// ---------------- per-layer kernels ----------------

// layer-0 gemm1 (standalone; later layers are fused into k_gemm2 phase C)
__global__ __launch_bounds__(256) void k_gemm1(const float* __restrict__ h,
                                               const u16* __restrict__ WpT_hi,
                                               const u16* __restrict__ WpT_lo,
                                               const float* __restrict__ pre_b,
                                               u16* __restrict__ Ph, u16* __restrict__ Qh,
                                               int M) {
    __shared__ u16 Ah[64 * 72], Al[64 * 72];
    __shared__ u16 Bh[128 * 72], Bl[128 * 72];
    int t = threadIdx.x, wid = t >> 6, lane = t & 63;
    int rows0 = blockIdx.x * 64;
    int quad = lane >> 4, l16 = lane & 15;
    int wm = wid & 1, wn = wid >> 1;

#pragma unroll
    for (int it = 0; it < 2; ++it) {
        int task = it * 256 + t;
        int r = task >> 3, seg = task & 7;
        int row = rows0 + r;
        float4 v0 = make_float4(0.f, 0.f, 0.f, 0.f), v1 = v0;
        if (row < M) {
            v0 = *(const float4*)&h[(size_t)row * 64 + seg * 8];
            v1 = *(const float4*)&h[(size_t)row * 64 + seg * 8 + 4];
        }
        s16x8 hv, lv;
        split8(v0, v1, hv, lv);
        *(s16x8*)&Ah[r * 72 + seg * 8] = hv;
        *(s16x8*)&Al[r * 72 + seg * 8] = lv;
    }
#pragma unroll
    for (int it = 0; it < 4; ++it) {
        int task = it * 256 + t;
        int c = task >> 3, seg = task & 7;
        *(s16x8*)&Bh[c * 72 + seg * 8] = *(const s16x8*)&WpT_hi[(size_t)c * 64 + seg * 8];
        *(s16x8*)&Bl[c * 72 + seg * 8] = *(const s16x8*)&WpT_lo[(size_t)c * 64 + seg * 8];
    }
    __syncthreads();

    f32x4 acc[2][4];
#pragma unroll
    for (int mt = 0; mt < 2; ++mt)
#pragma unroll
        for (int tt = 0; tt < 4; ++tt) acc[mt][tt] = (f32x4){0.f, 0.f, 0.f, 0.f};

#pragma unroll
    for (int c = 0; c < 2; ++c) {
        s16x8 ah[2], al[2];
#pragma unroll
        for (int mt = 0; mt < 2; ++mt) {
            int r = wm * 32 + mt * 16 + l16;
            ah[mt] = *(s16x8*)&Ah[r * 72 + c * 32 + quad * 8];
            al[mt] = *(s16x8*)&Al[r * 72 + c * 32 + quad * 8];
        }
#pragma unroll
        for (int tt = 0; tt < 4; ++tt) {
            int cc = wn * 64 + tt * 16 + l16;
            s16x8 bh = *(s16x8*)&Bh[cc * 72 + c * 32 + quad * 8];
            s16x8 bl = *(s16x8*)&Bl[cc * 72 + c * 32 + quad * 8];
#pragma unroll
            for (int mt = 0; mt < 2; ++mt) {
                acc[mt][tt] = MFMA(ah[mt], bh, acc[mt][tt]);
                acc[mt][tt] = MFMA(ah[mt], bl, acc[mt][tt]);
                if (wn == 0) acc[mt][tt] = MFMA(al[mt], bh, acc[mt][tt]);
            }
        }
    }

#pragma unroll
    for (int mt = 0; mt < 2; ++mt)
#pragma unroll
        for (int tt = 0; tt < 4; ++tt) {
            int col = wn * 64 + tt * 16 + l16;
#pragma unroll
            for (int r = 0; r < 4; ++r) {
                int row = rows0 + wm * 32 + mt * 16 + quad * 4 + r;
                if (row >= M) continue;
                float v = acc[mt][tt][r];
                if (col < 64) Ph[(size_t)row * 64 + col] = f2bf(v + pre_b[col]);
                else          Qh[(size_t)row * 64 + (col - 64)] = f2bf(v);
            }
        }
}

// aggregation (proven round 9/11): one wave handles TWO nodes, 8-deep unroll.
__global__ __launch_bounds__(256) void k_agg(const u16* __restrict__ Ph,
                                             const u16* __restrict__ Qh,
                                             const int* __restrict__ offs,
                                             const u16* __restrict__ ss,
                                             u16* __restrict__ AGGh, int N) {
    int w = threadIdx.x >> 6, lane = threadIdx.x & 63;
    int i0 = blockIdx.x * 8 + w * 2;
    int i1 = i0 + 1;
    if (i0 >= N) return;
    int beg0 = offs[i0], end0 = offs[i0 + 1];
    int beg1 = 0, end1 = 0;
    if (i1 < N) { beg1 = offs[i1]; end1 = offs[i1 + 1]; }
    float sum0 = 0.f, sqa0 = 0.f, sqb0 = 0.f, mx0 = -3.4e38f, mn0 = 3.4e38f;
    float sum1 = 0.f, sqa1 = 0.f, sqb1 = 0.f, mx1 = -3.4e38f, mn1 = 3.4e38f;
    int e0 = beg0, e1 = beg1;
    while (e0 + 8 <= end0 && e1 + 8 <= end1) {
        float qa[8], qb[8];
#pragma unroll
        for (int j = 0; j < 8; ++j) qa[j] = bf2f(Qh[((int)ss[e0 + j] << 6) + lane]);
#pragma unroll
        for (int j = 0; j < 8; ++j) qb[j] = bf2f(Qh[((int)ss[e1 + j] << 6) + lane]);
        sum0 += ((qa[0] + qa[1]) + (qa[2] + qa[3])) + ((qa[4] + qa[5]) + (qa[6] + qa[7]));
        sqa0 = fmaf(qa[0], qa[0], fmaf(qa[2], qa[2], fmaf(qa[4], qa[4], fmaf(qa[6], qa[6], sqa0))));
        sqb0 = fmaf(qa[1], qa[1], fmaf(qa[3], qa[3], fmaf(qa[5], qa[5], fmaf(qa[7], qa[7], sqb0))));
        mx0 = fmaxf(mx0, fmaxf(fmaxf(fmaxf(qa[0], qa[1]), fmaxf(qa[2], qa[3])),
                               fmaxf(fmaxf(qa[4], qa[5]), fmaxf(qa[6], qa[7]))));
        mn0 = fminf(mn0, fminf(fminf(fminf(qa[0], qa[1]), fminf(qa[2], qa[3])),
                               fminf(fminf(qa[4], qa[5]), fminf(qa[6], qa[7]))));
        sum1 += ((qb[0] + qb[1]) + (qb[2] + qb[3])) + ((qb[4] + qb[5]) + (qb[6] + qb[7]));
        sqa1 = fmaf(qb[0], qb[0], fmaf(qb[2], qb[2], fmaf(qb[4], qb[4], fmaf(qb[6], qb[6], sqa1))));
        sqb1 = fmaf(qb[1], qb[1], fmaf(qb[3], qb[3], fmaf(qb[5], qb[5], fmaf(qb[7], qb[7], sqb1))));
        mx1 = fmaxf(mx1, fmaxf(fmaxf(fmaxf(qb[0], qb[1]), fmaxf(qb[2], qb[3])),
                               fmaxf(fmaxf(qb[4], qb[5]), fmaxf(qb[6], qb[7]))));
        mn1 = fminf(mn1, fminf(fminf(fminf(qb[0], qb[1]), fminf(qb[2], qb[3])),
                               fminf(fminf(qb[4], qb[5]), fminf(qb[6], qb[7]))));
        e0 += 8; e1 += 8;
    }
    for (; e0 + 4 <= end0; e0 += 4) {
        float q0 = bf2f(Qh[((int)ss[e0 + 0] << 6) + lane]);
        float q1 = bf2f(Qh[((int)ss[e0 + 1] << 6) + lane]);
        float q2 = bf2f(Qh[((int)ss[e0 + 2] << 6) + lane]);
        float q3 = bf2f(Qh[((int)ss[e0 + 3] << 6) + lane]);
        sum0 += (q0 + q1) + (q2 + q3);
        sqa0 = fmaf(q0, q0, fmaf(q2, q2, sqa0));
        sqb0 = fmaf(q1, q1, fmaf(q3, q3, sqb0));
        mx0 = fmaxf(mx0, fmaxf(fmaxf(q0, q1), fmaxf(q2, q3)));
        mn0 = fminf(mn0, fminf(fminf(q0, q1), fminf(q2, q3)));
    }
    for (; e1 + 4 <= end1; e1 += 4) {
        float q0 = bf2f(Qh[((int)ss[e1 + 0] << 6) + lane]);
        float q1 = bf2f(Qh[((int)ss[e1 + 1] << 6) + lane]);
        float q2 = bf2f(Qh[((int)ss[e1 + 2] << 6) + lane]);
        float q3 = bf2f(Qh[((int)ss[e1 + 3] << 6) + lane]);
        sum1 += (q0 + q1) + (q2 + q3);
        sqa1 = fmaf(q0, q0, fmaf(q2, q2, sqa1));
        sqb1 = fmaf(q1, q1, fmaf(q3, q3, sqb1));
        mx1 = fmaxf(mx1, fmaxf(fmaxf(q0, q1), fmaxf(q2, q3)));
        mn1 = fminf(mn1, fminf(fminf(q0, q1), fminf(q2, q3)));
    }
    for (; e0 < end0; ++e0) {
        float q = bf2f(Qh[((int)ss[e0] << 6) + lane]);
        sum0 += q; sqa0 = fmaf(q, q, sqa0);
        mx0 = fmaxf(mx0, q); mn0 = fminf(mn0, q);
    }
    for (; e1 < end1; ++e1) {
        float q = bf2f(Qh[((int)ss[e1] << 6) + lane]);
        sum1 += q; sqa1 = fmaf(q, q, sqa1);
        mx1 = fmaxf(mx1, q); mn1 = fminf(mn1, q);
    }
    {
        int deg = end0 - beg0;
        float sq = sqa0 + sqb0;
        float p = bf2f(Ph[(i0 << 6) + lane]);
        float dc = fmaxf((float)deg, 1.f);
        float eq = sum0 / dc;
        float var = fmaxf(sq / dc - eq * eq, 0.f);
        float sd = sqrtf(var + EPSV);
        float mean, vmx, vmn;
        if (deg > 0) { mean = p + eq; vmx = p + mx0; vmn = p + mn0; }
        else         { mean = 0.f; vmx = 0.f; vmn = 0.f; }
        int o = (i0 << 8) + lane;
        AGGh[o] = f2bf(mean);
        AGGh[o + 64] = f2bf(vmx);
        AGGh[o + 128] = f2bf(vmn);
        AGGh[o + 192] = f2bf(sd);
    }
    if (i1 < N) {
        int deg = end1 - beg1;
        float sq = sqa1 + sqb1;
        float p = bf2f(Ph[(i1 << 6) + lane]);
        float dc = fmaxf((float)deg, 1.f);
        float eq = sum1 / dc;
        float var = fmaxf(sq / dc - eq * eq, 0.f);
        float sd = sqrtf(var + EPSV);
        float mean, vmx, vmn;
        if (deg > 0) { mean = p + eq; vmx = p + mx1; vmn = p + mn1; }
        else         { mean = 0.f; vmx = 0.f; vmn = 0.f; }
        int o = (i1 << 8) + lane;
        AGGh[o] = f2bf(mean);
        AGGh[o + 64] = f2bf(vmx);
        AGGh[o + 128] = f2bf(vmn);
        AGGh[o + 192] = f2bf(sd);
    }
}

// gemm2: 128-row blocks, 512 threads. Computes h' and (doNext) fuses
// gemm1(l+1) as phase C from in-register h' (same 51.2KB LDS reused).
// amp/att computed inline from deg+lsum (k_scalers removed).
__global__ __launch_bounds__(512) void k_gemm2(const float* __restrict__ hIn,
                                               const u16* __restrict__ AGGh,
                                               const u16* __restrict__ WT_hi,
                                               const u16* __restrict__ WT_lo,
                                               const float* __restrict__ bpp,
                                               const int* __restrict__ degp,
                                               const float* __restrict__ lsum,
                                               float* __restrict__ hOut,
                                               int doNext,
                                               const u16* __restrict__ WpN_hi,
                                               const u16* __restrict__ WpN_lo,
                                               const float* __restrict__ pre_bN,
                                               u16* __restrict__ PhN,
                                               u16* __restrict__ QhN, int M) {
    __shared__ u16 Ah[128 * 40], Al[128 * 40];  // [row][k-chunk 32], pitch 40
    __shared__ u16 Bh[192 * 40], Bl[192 * 40];  // [col][k-chunk 32], pitch 40
    int t = threadIdx.x, wid = t >> 6, lane = t & 63;
    int rows0 = blockIdx.x * 128;
    int quad = lane >> 4, l16 = lane & 15;
    int wm = wid & 3, wn = wid >> 2;

    f32x4 acc[2][6];  // [mt][cg + third*2]
#pragma unroll
    for (int mt = 0; mt < 2; ++mt)
#pragma unroll
        for (int tt = 0; tt < 6; ++tt) acc[mt][tt] = (f32x4){0.f, 0.f, 0.f, 0.f};

    // ---- Phase 1: k 0..63 over hIn (hi/lo split), cols 0:64 only ----
#pragma unroll
    for (int chunk = 0; chunk < 2; ++chunk) {
        {
            int r = t >> 2, seg = t & 3;
            int row = rows0 + r;
            float4 v0 = make_float4(0.f, 0.f, 0.f, 0.f), v1 = v0;
            if (row < M) {
                v0 = *(const float4*)&hIn[(size_t)row * 64 + chunk * 32 + seg * 8];
                v1 = *(const float4*)&hIn[(size_t)row * 64 + chunk * 32 + seg * 8 + 4];
            }
            s16x8 hv, lv;
            split8(v0, v1, hv, lv);
            *(s16x8*)&Ah[r * 40 + seg * 8] = hv;
            *(s16x8*)&Al[r * 40 + seg * 8] = lv;
        }
        if (t < 256) {
            int c = t >> 2, seg = t & 3;
            int k0g = chunk * 32;
            *(s16x8*)&Bh[c * 40 + seg * 8] = *(const s16x8*)&WT_hi[(size_t)c * 320 + k0g + seg * 8];
            *(s16x8*)&Bl[c * 40 + seg * 8] = *(const s16x8*)&WT_lo[(size_t)c * 320 + k0g + seg * 8];
        }
        __syncthreads();

        s16x8 ah[2], al[2];
#pragma unroll
        for (int mt = 0; mt < 2; ++mt) {
            int r = wm * 32 + mt * 16 + l16;
            ah[mt] = *(s16x8*)&Ah[r * 40 + quad * 8];
            al[mt] = *(s16x8*)&Al[r * 40 + quad * 8];
        }
#pragma unroll
        for (int cg = 0; cg < 2; ++cg) {
            int cc = wn * 32 + cg * 16 + l16;
            s16x8 bh = *(s16x8*)&Bh[cc * 40 + quad * 8];
            s16x8 bl = *(s16x8*)&Bl[cc * 40 + quad * 8];
#pragma unroll
            for (int mt = 0; mt < 2; ++mt) {
                acc[mt][cg] = MFMA(ah[mt], bh, acc[mt][cg]);
                acc[mt][cg] = MFMA(al[mt], bh, acc[mt][cg]);
                acc[mt][cg] = MFMA(ah[mt], bl, acc[mt][cg]);
            }
        }
        __syncthreads();
    }

    // ---- Phase 2: k 64..319 over AGGh (bf16 hi only), all 192 cols ----
    for (int chunk = 0; chunk < 8; ++chunk) {
        {
            int r = t >> 2, seg = t & 3;
            int row = rows0 + r;
            s16x8 v = (s16x8){0, 0, 0, 0, 0, 0, 0, 0};
            if (row < M) v = *(const s16x8*)&AGGh[(size_t)row * 256 + chunk * 32 + seg * 8];
            *(s16x8*)&Ah[r * 40 + seg * 8] = v;
        }
        {
            int k0g = 64 + chunk * 32;
#pragma unroll
            for (int it = 0; it < 2; ++it) {
                int task = it * 512 + t;
                if (task < 768) {
                    int c = task >> 2, seg = task & 3;
                    *(s16x8*)&Bh[c * 40 + seg * 8] = *(const s16x8*)&WT_hi[(size_t)c * 320 + k0g + seg * 8];
                    *(s16x8*)&Bl[c * 40 + seg * 8] = *(const s16x8*)&WT_lo[(size_t)c * 320 + k0g + seg * 8];
                }
            }
        }
        __syncthreads();

        s16x8 ah[2];
#pragma unroll
        for (int mt = 0; mt < 2; ++mt) {
            int r = wm * 32 + mt * 16 + l16;
            ah[mt] = *(s16x8*)&Ah[r * 40 + quad * 8];
        }
#pragma unroll
        for (int tt = 0; tt < 6; ++tt) {
            int cc = wn * 32 + (tt & 1) * 16 + (tt >> 1) * 64 + l16;
            s16x8 bh = *(s16x8*)&Bh[cc * 40 + quad * 8];
            s16x8 bl = *(s16x8*)&Bl[cc * 40 + quad * 8];
#pragma unroll
            for (int mt = 0; mt < 2; ++mt) {
                acc[mt][tt] = MFMA(ah[mt], bh, acc[mt][tt]);
                acc[mt][tt] = MFMA(ah[mt], bl, acc[mt][tt]);
            }
        }
        __syncthreads();
    }

    // ---- Epilogue: combine thirds (amp/att inline), residual + bias ----
    float hv[2][2][4];  // h' values this thread owns: [mt][cg][r]
    float avg = *lsum / (float)M;
#pragma unroll
    for (int mt = 0; mt < 2; ++mt)
#pragma unroll
        for (int r = 0; r < 4; ++r) {
            int row = rows0 + wm * 32 + mt * 16 + quad * 4 + r;
            float am = 1.f, at = 1.f, hin0 = 0.f, hin1 = 0.f;
            if (row < M) {
                float dc = fmaxf((float)degp[row], 1.f);
                float ld = logf(dc + 1.f);
                am = ld / avg;
                at = avg / ld;
                hin0 = hIn[(size_t)row * 64 + wn * 32 + l16];
                hin1 = hIn[(size_t)row * 64 + wn * 32 + 16 + l16];
            }
#pragma unroll
            for (int cg = 0; cg < 2; ++cg) {
                int col = wn * 32 + cg * 16 + l16;
                float v = acc[mt][cg][r] + am * acc[mt][cg + 2][r] + at * acc[mt][cg + 4][r]
                        + (cg == 0 ? hin0 : hin1) + bpp[col];
                hv[mt][cg][r] = v;
                if (row < M) hOut[(size_t)row * 64 + col] = v;
            }
        }

    // ---- Phase C (doNext): gemm1(l+1) from in-register h' ----
    if (doNext) {
        f32x4 acc2[2][4];
#pragma unroll
        for (int mt = 0; mt < 2; ++mt)
#pragma unroll
            for (int tt = 0; tt < 4; ++tt) acc2[mt][tt] = (f32x4){0.f, 0.f, 0.f, 0.f};

#pragma unroll
        for (int chunk = 0; chunk < 2; ++chunk) {
            // stage WpN chunk: 128 cols x 32 k
            {
                int c = t >> 2, seg = t & 3;  // 512 tasks
                *(s16x8*)&Bh[c * 40 + seg * 8] = *(const s16x8*)&WpN_hi[(size_t)c * 64 + chunk * 32 + seg * 8];
                *(s16x8*)&Bl[c * 40 + seg * 8] = *(const s16x8*)&WpN_lo[(size_t)c * 64 + chunk * 32 + seg * 8];
            }
            // stage h' chunk: threads whose cols fall in this chunk (wn==chunk)
            if (wn == chunk) {
#pragma unroll
                for (int mt = 0; mt < 2; ++mt)
#pragma unroll
                    for (int cg = 0; cg < 2; ++cg) {
                        int lc = cg * 16 + l16;  // local col 0..31
#pragma unroll
                        for (int r = 0; r < 4; ++r) {
                            int rl = wm * 32 + mt * 16 + quad * 4 + r;
                            float v = hv[mt][cg][r];
                            u16 hi = f2bf(v);
                            Ah[rl * 40 + lc] = hi;
                            Al[rl * 40 + lc] = f2bf(v - bf2f(hi));
                        }
                    }
            }
            __syncthreads();

            s16x8 ah[2], al[2];
#pragma unroll
            for (int mt = 0; mt < 2; ++mt) {
                int r = wm * 32 + mt * 16 + l16;
                ah[mt] = *(s16x8*)&Ah[r * 40 + quad * 8];
                al[mt] = *(s16x8*)&Al[r * 40 + quad * 8];
            }
#pragma unroll
            for (int tt = 0; tt < 4; ++tt) {
                int cc = wn * 64 + tt * 16 + l16;
                s16x8 bh = *(s16x8*)&Bh[cc * 40 + quad * 8];
                s16x8 bl = *(s16x8*)&Bl[cc * 40 + quad * 8];
#pragma unroll
                for (int mt = 0; mt < 2; ++mt) {
                    acc2[mt][tt] = MFMA(ah[mt], bh, acc2[mt][tt]);
                    acc2[mt][tt] = MFMA(ah[mt], bl, acc2[mt][tt]);
                    if (wn == 0) acc2[mt][tt] = MFMA(al[mt], bh, acc2[mt][tt]);
                }
            }
            __syncthreads();
        }

#pragma unroll
        for (int mt = 0; mt < 2; ++mt)
#pragma unroll
            for (int tt = 0; tt < 4; ++tt) {
                int col = wn * 64 + tt * 16 + l16;
#pragma unroll
                for (int r = 0; r < 4; ++r) {
                    int row = rows0 + wm * 32 + mt * 16 + quad * 4 + r;
                    if (row >= M) continue;
                    float v = acc2[mt][tt][r];
                    if (col < 64) PhN[(size_t)row * 64 + col] = f2bf(v + pre_bN[col]);
                    else          QhN[(size_t)row * 64 + (col - 64)] = f2bf(v);
                }
            }
    }
}

// ---------------- launch ----------------

extern "C" void kernel_launch(void* const* d_in, const int* in_sizes, int n_in,
                              void* d_out, int out_size, void* d_ws, size_t ws_size,
                              hipStream_t stream) {
    const float* x      = (const float*)d_in[0];
    const int*   ei     = (const int*)d_in[1];
    const float* pre_w  = (const float*)d_in[2];
    const float* pre_b  = (const float*)d_in[3];
    const float* post_w = (const float*)d_in[4];
    const float* post_b = (const float*)d_in[5];
    const float* lin_w  = (const float*)d_in[6];
    const float* lin_b  = (const float*)d_in[7];

    const int N = in_sizes[0] / 64;
    const int E = in_sizes[1] / 2;
    const int L = in_sizes[2] / (128 * 64);

    const int* srcIdx = ei;
    const int* dstIdx = ei + E;

    char* ws = (char*)d_ws;
    size_t off = 0;
    auto alloc = [&](size_t bytes) {
        void* p = ws + off;
        off += (bytes + 255) & ~(size_t)255;
        return p;
    };
    int*      deg        = (int*)alloc((size_t)N * 4);
    int*      offs       = (int*)alloc((size_t)(N + 1) * 4);
    u16*      srcSorted  = (u16*)alloc((size_t)E * 2);
    unsigned* edgeTmp    = (unsigned*)alloc((size_t)NBP * CAP * 4);
    int*      bucketCur  = (int*)alloc(NBP * 4);
    float*    lsum       = (float*)alloc(256);
    u16*      WpT_hi     = (u16*)alloc((size_t)L * 128 * 64 * 2);
    u16*      WpT_lo     = (u16*)alloc((size_t)L * 128 * 64 * 2);
    u16*      WT_hi      = (u16*)alloc((size_t)L * 192 * 320 * 2);
    u16*      WT_lo      = (u16*)alloc((size_t)L * 192 * 320 * 2);
    float*    bpp        = (float*)alloc((size_t)L * 64 * 4);
    u16*      Ph         = (u16*)alloc((size_t)N * 64 * 2);
    u16*      Qh         = (u16*)alloc((size_t)N * 64 * 2);
    u16*      AGGh       = (u16*)alloc((size_t)N * 256 * 2);
    float*    hA         = (float*)alloc((size_t)N * 64 * 4);
    float*    hB         = (float*)alloc((size_t)N * 64 * 4);
    (void)ws_size;

    int NB = (N + 255) >> 8;
    int NB1 = (E + EPB3 - 1) / EPB3;
    int initBlk = (NBP + 191) / 192;

    k_wprep<<<dim3(449 + initBlk, L), 192, 0, stream>>>(
        pre_w, post_w, post_b, lin_w, lin_b, WpT_hi, WpT_lo, WT_hi, WT_lo, bpp,
        bucketCur, lsum);
    k_bucket3<<<NB1, 512, 0, stream>>>(srcIdx, dstIdx, E, bucketCur, edgeTmp);
    k_csort2<<<NB, 512, 0, stream>>>(edgeTmp, bucketCur, deg, offs, lsum,
                                     srcSorted, N, E, NB);

    int gblk = (N + 63) / 64;
    int gblk2 = (N + 127) / 128;
    k_gemm1<<<gblk, 256, 0, stream>>>(x, WpT_hi, WpT_lo, pre_b, Ph, Qh, N);

    const float* hIn = x;
    float* hbuf[2] = {hA, hB};
    for (int l = 0; l < L; ++l) {
        float* hOut = (l == L - 1) ? (float*)d_out : hbuf[l & 1];
        int dn = (l < L - 1) ? 1 : 0;
        int ln = dn ? (l + 1) : 0;
        k_agg<<<(N + 7) / 8, 256, 0, stream>>>(Ph, Qh, offs, srcSorted, AGGh, N);
        k_gemm2<<<gblk2, 512, 0, stream>>>(hIn, AGGh,
                                           WT_hi + (size_t)l * 192 * 320,
                                           WT_lo + (size_t)l * 192 * 320,
                                           bpp + (size_t)l * 64,
                                           deg, lsum, hOut, dn,
                                           WpT_hi + (size_t)ln * 128 * 64,
                                           WpT_lo + (size_t)ln * 128 * 64,
                                           pre_b + (size_t)ln * 64,
                                           Ph, Qh, N);
        hIn = hOut;
    }
}